// Round 7
// baseline (2045.027 us; speedup 1.0000x reference)
//
#include <hip/hip_runtime.h>

#define T_   256
#define F_   32
#define NBB  8      // batch elements per block -> 512 blocks = 2 blocks/CU
#define TPB  512    // 8 waves: 4x L1, 2x L2, 2x X-staging
#define IMR  16     // image rows (MFMA fragment col dim; rows 8..15 are dummy)
#define IMW  104    // img row width in ushorts

typedef __attribute__((ext_vector_type(8))) short bf16x8;
typedef __attribute__((ext_vector_type(4))) float f32x4;
typedef __attribute__((ext_vector_type(4))) unsigned short ush4;

__device__ __forceinline__ float sigmoid_fast(float x){ return __fdividef(1.f, 1.f + __expf(-x)); }
__device__ __forceinline__ float tanh_fast(float x){ float e = __expf(2.f*x); return 1.f - __fdividef(2.f, e + 1.f); }

__device__ __forceinline__ unsigned short bf16_rne(float x){
    unsigned u = __float_as_uint(x);
    u += 0x7FFF + ((u >> 16) & 1);
    return (unsigned short)(u >> 16);
}
__device__ __forceinline__ void bf16_split(float x, unsigned short& h, unsigned short& l){
    h = bf16_rne(x);
    float xr = __uint_as_float(((unsigned)h) << 16);
    l = bf16_rne(x - xr);
}
__device__ __forceinline__ void make_frags(const float* __restrict__ p8, bf16x8& fh, bf16x8& fl){
    #pragma unroll
    for (int e = 0; e < 8; ++e){
        unsigned short h, l; bf16_split(p8[e], h, l);
        fh[e] = (short)h; fl[e] = (short)l;
    }
}

#define MFMA(A,B,C) __builtin_amdgcn_mfma_f32_16x16x32_bf16((A),(B),(C),0,0,0)

// (512,4): 4 waves/EU -> 128-VGPR cap (round-6 natural use was 124, fits) and
// guarantees 2 blocks/CU co-residency so two independent recurrences interleave.
__global__ __launch_bounds__(TPB, 4) void lstm_mfma(
    const float* __restrict__ x,      // [4096,256,32]
    const float* __restrict__ W_ih1,  // [256,32]
    const float* __restrict__ W_hh1,  // [256,64]
    const float* __restrict__ b_ih1,  // [256]
    const float* __restrict__ b_hh1,  // [256]
    const float* __restrict__ W_ih2,  // [128,64]
    const float* __restrict__ W_hh2,  // [128,32]
    const float* __restrict__ b_ih2,  // [128]
    const float* __restrict__ b_hh2,  // [128]
    const float* __restrict__ W_fc1,  // [16,32]
    const float* __restrict__ b_fc1,  // [16]
    const float* __restrict__ W_fc2,  // [1,16]
    const float* __restrict__ b_fc2,  // [1]
    float* __restrict__ out)          // [4096]
{
    const int tid  = threadIdx.x;
    const int lane = tid & 63;
    const int wid  = tid >> 6;        // 0..7
    const int bb   = lane & 15;       // fragment col = batch (8..15 dummy)
    const int kg   = (lane >> 4) & 3; // k-group of 8
    const int b0   = blockIdx.x * NBB;

    // img1 = [x(32)|h1(64)], img2 = [h1(64)|h2(32)]; hi/lo bf16, double-buffered
    __shared__ __align__(16) unsigned short i1h[2][IMR][IMW], i1l[2][IMR][IMW];
    __shared__ __align__(16) unsigned short i2h[2][IMR][IMW], i2l[2][IMR][IMW];
    __shared__ float hfin[IMR][32];
    __shared__ float hd[NBB][16];

    // ===== role-specific state =====
    bf16x8 wh[4][3], wl[4][3];
    f32x4  bfr[4];
    float  cc[4] = {0.f,0.f,0.f,0.f};
    int    uo = 0;

    if (wid < 4){
        uo = 16*wid + 4*kg;
        #pragma unroll
        for (int g = 0; g < 4; ++g){
            const int r = 64*g + 16*wid + bb;
            make_frags(&W_ih1[r*32 +      8*kg], wh[g][0], wl[g][0]);
            make_frags(&W_hh1[r*64 +      8*kg], wh[g][1], wl[g][1]);
            make_frags(&W_hh1[r*64 + 32 + 8*kg], wh[g][2], wl[g][2]);
            #pragma unroll
            for (int q = 0; q < 4; ++q){
                const int row = 64*g + 16*wid + 4*kg + q;
                bfr[g][q] = b_ih1[row] + b_hh1[row];
            }
        }
    } else if (wid < 6){
        const int j = wid - 4;
        uo = 16*j + 4*kg;
        #pragma unroll
        for (int g = 0; g < 4; ++g){
            const int r = 32*g + 16*j + bb;
            make_frags(&W_ih2[r*64 +      8*kg], wh[g][0], wl[g][0]);
            make_frags(&W_ih2[r*64 + 32 + 8*kg], wh[g][1], wl[g][1]);
            make_frags(&W_hh2[r*32 +      8*kg], wh[g][2], wl[g][2]);
            #pragma unroll
            for (int q = 0; q < 4; ++q){
                const int row = 32*g + 16*j + 4*kg + q;
                bfr[g][q] = b_ih2[row] + b_hh2[row];
            }
        }
    }

    // X waves (6,7): thread owns (batch xb_, float4-quad xf4); 64 thr = 8b x 8q.
    // Wave 6 owns even 8-step groups, wave 7 odd; loads burst once per 16 steps.
    const int xw  = wid - 6;
    const int xb_ = lane >> 3;
    const int xf4 = lane & 7;
    const size_t xbase = (size_t)(b0 + xb_) * (T_*F_) + 4*xf4;
    float4 xr0, xr1, xr2, xr3, xr4, xr5, xr6, xr7;

    if (wid >= 6){
        const size_t gb = (size_t)(8 * xw) * F_;   // group 0 / group 1
        xr0 = *(const float4*)&x[xbase + gb + 0*F_];
        xr1 = *(const float4*)&x[xbase + gb + 1*F_];
        xr2 = *(const float4*)&x[xbase + gb + 2*F_];
        xr3 = *(const float4*)&x[xbase + gb + 3*F_];
        xr4 = *(const float4*)&x[xbase + gb + 4*F_];
        xr5 = *(const float4*)&x[xbase + gb + 5*F_];
        xr6 = *(const float4*)&x[xbase + gb + 6*F_];
        xr7 = *(const float4*)&x[xbase + gb + 7*F_];
    }

    // ===== init: zero images, stage x(0) =====
    for (int i = tid; i < 2*IMR*IMW; i += TPB){
        (&i1h[0][0][0])[i] = 0; (&i1l[0][0][0])[i] = 0;
        (&i2h[0][0][0])[i] = 0; (&i2l[0][0][0])[i] = 0;
    }
    __syncthreads();
    if (wid == 6){
        ush4 HH, HL;
        unsigned short h, l;
        bf16_split(xr0.x, h, l); HH[0]=h; HL[0]=l;
        bf16_split(xr0.y, h, l); HH[1]=h; HL[1]=l;
        bf16_split(xr0.z, h, l); HH[2]=h; HL[2]=l;
        bf16_split(xr0.w, h, l); HH[3]=h; HL[3]=l;
        *(ush4*)&i1h[0][xb_][4*xf4] = HH;
        *(ush4*)&i1l[0][xb_][4*xf4] = HL;
        xr0=xr1; xr1=xr2; xr2=xr3; xr3=xr4; xr4=xr5; xr5=xr6; xr6=xr7;
    }
    __syncthreads();

    // ===== main loop: ONE barrier per step; L2 lags L1 by one step =====
    for (int t = 0; t <= T_; ++t){
        const int cur = t & 1, nxt = cur ^ 1;

        if (wid < 4){
            if (t < T_){
                const unsigned short* ph = &i1h[cur][0][0] + bb*IMW + 8*kg;
                const unsigned short* pl = &i1l[cur][0][0] + bb*IMW + 8*kg;
                bf16x8 vh[3], vl[3];
                #pragma unroll
                for (int kb = 0; kb < 3; ++kb){
                    vh[kb] = *(const bf16x8*)(ph + 32*kb);
                    vl[kb] = *(const bf16x8*)(pl + 32*kb);
                }
                f32x4 A0[4], A1[4];
                #pragma unroll
                for (int g = 0; g < 4; ++g){ A0[g] = bfr[g]; A1[g] = {0.f,0.f,0.f,0.f}; }
                #pragma unroll
                for (int kb = 0; kb < 3; ++kb)
                    #pragma unroll
                    for (int g = 0; g < 4; ++g) A0[g] = MFMA(wh[g][kb], vh[kb], A0[g]);
                #pragma unroll
                for (int kb = 0; kb < 3; ++kb)
                    #pragma unroll
                    for (int g = 0; g < 4; ++g) A1[g] = MFMA(wl[g][kb], vh[kb], A1[g]);
                #pragma unroll
                for (int g = 0; g < 4; ++g) A0[g] = MFMA(wh[g][0], vl[0], A0[g]);
                #pragma unroll
                for (int g = 0; g < 4; ++g){
                    A1[g] = MFMA(wh[g][1], vl[1], A1[g]);
                    A1[g] = MFMA(wh[g][2], vl[2], A1[g]);
                }
                ush4 HH, HL;
                #pragma unroll
                for (int q = 0; q < 4; ++q){
                    const float i_ = sigmoid_fast(A0[0][q] + A1[0][q]);
                    const float f_ = sigmoid_fast(A0[1][q] + A1[1][q]);
                    const float g_ = tanh_fast   (A0[2][q] + A1[2][q]);
                    const float o_ = sigmoid_fast(A0[3][q] + A1[3][q]);
                    cc[q] = fmaf(f_, cc[q], i_ * g_);
                    const float h1v = o_ * tanh_fast(cc[q]);
                    unsigned short h, l; bf16_split(h1v, h, l);
                    HH[q] = h; HL[q] = l;
                }
                *(ush4*)&i1h[nxt][bb][32 + uo] = HH;
                *(ush4*)&i1l[nxt][bb][32 + uo] = HL;
                *(ush4*)&i2h[nxt][bb][uo]      = HH;
                *(ush4*)&i2l[nxt][bb][uo]      = HL;
            }
        } else if (wid < 6){
            if (t > 0){   // computes h2(t-1)
                const unsigned short* ph = &i2h[cur][0][0] + bb*IMW + 8*kg;
                const unsigned short* pl = &i2l[cur][0][0] + bb*IMW + 8*kg;
                bf16x8 vh[3], vl[3];
                #pragma unroll
                for (int kb = 0; kb < 3; ++kb){
                    vh[kb] = *(const bf16x8*)(ph + 32*kb);
                    vl[kb] = *(const bf16x8*)(pl + 32*kb);
                }
                f32x4 A0[4], A1[4];
                #pragma unroll
                for (int g = 0; g < 4; ++g){ A0[g] = bfr[g]; A1[g] = {0.f,0.f,0.f,0.f}; }
                #pragma unroll
                for (int kb = 0; kb < 3; ++kb)
                    #pragma unroll
                    for (int g = 0; g < 4; ++g) A0[g] = MFMA(wh[g][kb], vh[kb], A0[g]);
                #pragma unroll
                for (int kb = 0; kb < 3; ++kb)
                    #pragma unroll
                    for (int g = 0; g < 4; ++g) A1[g] = MFMA(wl[g][kb], vh[kb], A1[g]);
                #pragma unroll
                for (int g = 0; g < 4; ++g) A0[g] = MFMA(wh[g][0], vl[0], A0[g]);
                #pragma unroll
                for (int g = 0; g < 4; ++g){
                    A1[g] = MFMA(wh[g][1], vl[1], A1[g]);
                    A1[g] = MFMA(wh[g][2], vl[2], A1[g]);
                }
                ush4 HH, HL;
                f32x4 hv;
                #pragma unroll
                for (int q = 0; q < 4; ++q){
                    const float i_ = sigmoid_fast(A0[0][q] + A1[0][q]);
                    const float f_ = sigmoid_fast(A0[1][q] + A1[1][q]);
                    const float g_ = tanh_fast   (A0[2][q] + A1[2][q]);
                    const float o_ = sigmoid_fast(A0[3][q] + A1[3][q]);
                    cc[q] = fmaf(f_, cc[q], i_ * g_);
                    const float h2v = o_ * tanh_fast(cc[q]);
                    unsigned short h, l; bf16_split(h2v, h, l);
                    HH[q] = h; HL[q] = l; hv[q] = h2v;
                }
                *(ush4*)&i2h[nxt][bb][64 + uo] = HH;
                *(ush4*)&i2l[nxt][bb][64 + uo] = HL;
                if (t == T_) *(f32x4*)&hfin[bb][uo] = hv;
            }
        } else {
            const int tp1 = t + 1;
            if (tp1 < T_ && (((tp1 >> 3) & 1) == xw)){
                // stage x(tp1) from xr0 (register-rotated, all static indices)
                ush4 HH, HL;
                unsigned short h, l;
                bf16_split(xr0.x, h, l); HH[0]=h; HL[0]=l;
                bf16_split(xr0.y, h, l); HH[1]=h; HL[1]=l;
                bf16_split(xr0.z, h, l); HH[2]=h; HL[2]=l;
                bf16_split(xr0.w, h, l); HH[3]=h; HL[3]=l;
                *(ush4*)&i1h[nxt][xb_][4*xf4] = HH;
                *(ush4*)&i1l[nxt][xb_][4*xf4] = HL;
                xr0=xr1; xr1=xr2; xr2=xr3; xr3=xr4; xr4=xr5; xr5=xr6; xr6=xr7;
                if ((tp1 & 7) == 7){
                    const int gn = (tp1 >> 3) + 2;   // next group this wave owns
                    if (gn <= T_/8 - 1){
                        const size_t gb = xbase + (size_t)(8*gn) * F_;
                        // burst-issue 8 loads; vmcnt drain gates only ONE barrier
                        // per 16 steps, 8 steps of compute hide the latency
                        xr0 = *(const float4*)&x[gb + 0*F_];
                        xr1 = *(const float4*)&x[gb + 1*F_];
                        xr2 = *(const float4*)&x[gb + 2*F_];
                        xr3 = *(const float4*)&x[gb + 3*F_];
                        xr4 = *(const float4*)&x[gb + 4*F_];
                        xr5 = *(const float4*)&x[gb + 5*F_];
                        xr6 = *(const float4*)&x[gb + 6*F_];
                        xr7 = *(const float4*)&x[gb + 7*F_];
                    }
                }
            }
        }
        __syncthreads();
    }

    // ===== head: fc1(16)+relu, fc2(1) =====
    if (tid < NBB * 16){
        const int b = tid >> 4, j2 = tid & 15;
        float a = b_fc1[j2];
        #pragma unroll
        for (int k = 0; k < 32; ++k) a = fmaf(W_fc1[j2*32 + k], hfin[b][k], a);
        hd[b][j2] = fmaxf(a, 0.f);
    }
    __syncthreads();
    if (tid < NBB){
        float a = b_fc2[0];
        #pragma unroll
        for (int k = 0; k < 16; ++k) a = fmaf(W_fc2[k], hd[tid][k], a);
        out[b0 + tid] = a;
    }
}

extern "C" void kernel_launch(void* const* d_in, const int* in_sizes, int n_in,
                              void* d_out, int out_size, void* d_ws, size_t ws_size,
                              hipStream_t stream) {
    const float* x     = (const float*)d_in[0];
    const float* W_ih1 = (const float*)d_in[1];
    const float* W_hh1 = (const float*)d_in[2];
    const float* b_ih1 = (const float*)d_in[3];
    const float* b_hh1 = (const float*)d_in[4];
    const float* W_ih2 = (const float*)d_in[5];
    const float* W_hh2 = (const float*)d_in[6];
    const float* b_ih2 = (const float*)d_in[7];
    const float* b_hh2 = (const float*)d_in[8];
    const float* W_fc1 = (const float*)d_in[9];
    const float* b_fc1 = (const float*)d_in[10];
    const float* W_fc2 = (const float*)d_in[11];
    const float* b_fc2 = (const float*)d_in[12];
    float* out = (float*)d_out;

    const int B = in_sizes[0] / (T_ * F_);   // 4096
    dim3 grid(B / NBB), block(TPB);          // 512 blocks = 2 per CU
    hipLaunchKernelGGL(lstm_mfma, grid, block, 0, stream,
                       x, W_ih1, W_hh1, b_ih1, b_hh1,
                       W_ih2, W_hh2, b_ih2, b_hh2,
                       W_fc1, b_fc1, W_fc2, b_fc2, out);
}

// Round 8
// 955.600 us; speedup vs baseline: 2.1400x; 2.1400x over previous
//
#include <hip/hip_runtime.h>

#define T_   256
#define F_   32
#define NBB  8      // batch elements per block -> 512 blocks = 2 blocks/CU
#define TPB  512    // 8 waves: 4x L1, 2x L2, 2x X-staging
#define IMR  16     // image rows (MFMA fragment col dim; rows 8..15 are dummy)
#define IMW  104    // img row width in ushorts

typedef __attribute__((ext_vector_type(8))) short bf16x8;
typedef __attribute__((ext_vector_type(4))) float f32x4;
typedef __attribute__((ext_vector_type(4))) unsigned short ush4;

__device__ __forceinline__ float sigmoid_fast(float x){ return __fdividef(1.f, 1.f + __expf(-x)); }
__device__ __forceinline__ float tanh_fast(float x){ float e = __expf(2.f*x); return 1.f - __fdividef(2.f, e + 1.f); }

__device__ __forceinline__ unsigned short bf16_rne(float x){
    unsigned u = __float_as_uint(x);
    u += 0x7FFF + ((u >> 16) & 1);
    return (unsigned short)(u >> 16);
}
__device__ __forceinline__ void bf16_split(float x, unsigned short& h, unsigned short& l){
    h = bf16_rne(x);
    float xr = __uint_as_float(((unsigned)h) << 16);
    l = bf16_rne(x - xr);
}
__device__ __forceinline__ void make_frags(const float* __restrict__ p8, bf16x8& fh, bf16x8& fl){
    #pragma unroll
    for (int e = 0; e < 8; ++e){
        unsigned short h, l; bf16_split(p8[e], h, l);
        fh[e] = (short)h; fl[e] = (short)l;
    }
}

#define MFMA(A,B,C) __builtin_amdgcn_mfma_f32_16x16x32_bf16((A),(B),(C),0,0,0)

// Step barrier WITHOUT vmcnt drain: LDS writes are made visible (lgkmcnt(0))
// but the x-waves' in-flight global loads (register destinations, consumed
// steps later) stay outstanding across the barrier. __syncthreads() would
// force vmcnt(0) = ~900cy HBM-latency on the critical path every 8 steps.
__device__ __forceinline__ void step_barrier(){
    asm volatile("s_waitcnt lgkmcnt(0)" ::: "memory");
    __builtin_amdgcn_s_barrier();
}

// (512,2): 256-VGPR cap; natural allocation ~124 (round-6 evidence) which
// permits 4 waves/EU -> 2 co-resident blocks/CU. NEVER use min-waves>=4 here:
// it caps VGPRs at/below 64 and spills the weight fragments (rounds 2 & 7).
__global__ __launch_bounds__(TPB, 2) void lstm_mfma(
    const float* __restrict__ x,      // [4096,256,32]
    const float* __restrict__ W_ih1,  // [256,32]
    const float* __restrict__ W_hh1,  // [256,64]
    const float* __restrict__ b_ih1,  // [256]
    const float* __restrict__ b_hh1,  // [256]
    const float* __restrict__ W_ih2,  // [128,64]
    const float* __restrict__ W_hh2,  // [128,32]
    const float* __restrict__ b_ih2,  // [128]
    const float* __restrict__ b_hh2,  // [128]
    const float* __restrict__ W_fc1,  // [16,32]
    const float* __restrict__ b_fc1,  // [16]
    const float* __restrict__ W_fc2,  // [1,16]
    const float* __restrict__ b_fc2,  // [1]
    float* __restrict__ out)          // [4096]
{
    const int tid  = threadIdx.x;
    const int lane = tid & 63;
    const int wid  = tid >> 6;        // 0..7
    const int bb   = lane & 15;       // fragment col = batch (8..15 dummy)
    const int kg   = (lane >> 4) & 3; // k-group of 8
    const int b0   = blockIdx.x * NBB;

    // img1 = [x(32)|h1(64)], img2 = [h1(64)|h2(32)]; hi/lo bf16, double-buffered
    __shared__ __align__(16) unsigned short i1h[2][IMR][IMW], i1l[2][IMR][IMW];
    __shared__ __align__(16) unsigned short i2h[2][IMR][IMW], i2l[2][IMR][IMW];
    __shared__ float hfin[IMR][32];
    __shared__ float hd[NBB][16];

    // ===== role-specific state =====
    bf16x8 wh[4][3], wl[4][3];
    f32x4  bfr[4];
    float  cc[4] = {0.f,0.f,0.f,0.f};
    int    uo = 0;

    if (wid < 4){
        uo = 16*wid + 4*kg;
        #pragma unroll
        for (int g = 0; g < 4; ++g){
            const int r = 64*g + 16*wid + bb;
            make_frags(&W_ih1[r*32 +      8*kg], wh[g][0], wl[g][0]);
            make_frags(&W_hh1[r*64 +      8*kg], wh[g][1], wl[g][1]);
            make_frags(&W_hh1[r*64 + 32 + 8*kg], wh[g][2], wl[g][2]);
            #pragma unroll
            for (int q = 0; q < 4; ++q){
                const int row = 64*g + 16*wid + 4*kg + q;
                bfr[g][q] = b_ih1[row] + b_hh1[row];
            }
        }
    } else if (wid < 6){
        const int j = wid - 4;
        uo = 16*j + 4*kg;
        #pragma unroll
        for (int g = 0; g < 4; ++g){
            const int r = 32*g + 16*j + bb;
            make_frags(&W_ih2[r*64 +      8*kg], wh[g][0], wl[g][0]);
            make_frags(&W_ih2[r*64 + 32 + 8*kg], wh[g][1], wl[g][1]);
            make_frags(&W_hh2[r*32 +      8*kg], wh[g][2], wl[g][2]);
            #pragma unroll
            for (int q = 0; q < 4; ++q){
                const int row = 32*g + 16*j + 4*kg + q;
                bfr[g][q] = b_ih2[row] + b_hh2[row];
            }
        }
    }

    // X waves (6,7): thread owns (batch xb_, float4-quad xf4); 64 thr = 8b x 8q.
    // Wave 6 owns even 8-step groups, wave 7 odd; loads burst once per 16 steps.
    const int xw  = wid - 6;
    const int xb_ = lane >> 3;
    const int xf4 = lane & 7;
    const size_t xbase = (size_t)(b0 + xb_) * (T_*F_) + 4*xf4;
    float4 xr0, xr1, xr2, xr3, xr4, xr5, xr6, xr7;

    if (wid >= 6){
        const size_t gb = (size_t)(8 * xw) * F_;   // group 0 / group 1
        xr0 = *(const float4*)&x[xbase + gb + 0*F_];
        xr1 = *(const float4*)&x[xbase + gb + 1*F_];
        xr2 = *(const float4*)&x[xbase + gb + 2*F_];
        xr3 = *(const float4*)&x[xbase + gb + 3*F_];
        xr4 = *(const float4*)&x[xbase + gb + 4*F_];
        xr5 = *(const float4*)&x[xbase + gb + 5*F_];
        xr6 = *(const float4*)&x[xbase + gb + 6*F_];
        xr7 = *(const float4*)&x[xbase + gb + 7*F_];
    }

    // ===== init: zero images, stage x(0) =====
    for (int i = tid; i < 2*IMR*IMW; i += TPB){
        (&i1h[0][0][0])[i] = 0; (&i1l[0][0][0])[i] = 0;
        (&i2h[0][0][0])[i] = 0; (&i2l[0][0][0])[i] = 0;
    }
    __syncthreads();
    if (wid == 6){
        ush4 HH, HL;
        unsigned short h, l;
        bf16_split(xr0.x, h, l); HH[0]=h; HL[0]=l;
        bf16_split(xr0.y, h, l); HH[1]=h; HL[1]=l;
        bf16_split(xr0.z, h, l); HH[2]=h; HL[2]=l;
        bf16_split(xr0.w, h, l); HH[3]=h; HL[3]=l;
        *(ush4*)&i1h[0][xb_][4*xf4] = HH;
        *(ush4*)&i1l[0][xb_][4*xf4] = HL;
        xr0=xr1; xr1=xr2; xr2=xr3; xr3=xr4; xr4=xr5; xr5=xr6; xr6=xr7;
    }
    __syncthreads();

    // ===== main loop: ONE raw barrier per step; L2 lags L1 by one step =====
    for (int t = 0; t <= T_; ++t){
        const int cur = t & 1, nxt = cur ^ 1;

        if (wid < 4){
            if (t < T_){
                const unsigned short* ph = &i1h[cur][0][0] + bb*IMW + 8*kg;
                const unsigned short* pl = &i1l[cur][0][0] + bb*IMW + 8*kg;
                bf16x8 vh[3], vl[3];
                #pragma unroll
                for (int kb = 0; kb < 3; ++kb){
                    vh[kb] = *(const bf16x8*)(ph + 32*kb);
                    vl[kb] = *(const bf16x8*)(pl + 32*kb);
                }
                f32x4 A0[4], A1[4];
                #pragma unroll
                for (int g = 0; g < 4; ++g){ A0[g] = bfr[g]; A1[g] = {0.f,0.f,0.f,0.f}; }
                #pragma unroll
                for (int kb = 0; kb < 3; ++kb)
                    #pragma unroll
                    for (int g = 0; g < 4; ++g) A0[g] = MFMA(wh[g][kb], vh[kb], A0[g]);
                #pragma unroll
                for (int kb = 0; kb < 3; ++kb)
                    #pragma unroll
                    for (int g = 0; g < 4; ++g) A1[g] = MFMA(wl[g][kb], vh[kb], A1[g]);
                #pragma unroll
                for (int g = 0; g < 4; ++g) A0[g] = MFMA(wh[g][0], vl[0], A0[g]);
                #pragma unroll
                for (int g = 0; g < 4; ++g){
                    A1[g] = MFMA(wh[g][1], vl[1], A1[g]);
                    A1[g] = MFMA(wh[g][2], vl[2], A1[g]);
                }
                ush4 HH, HL;
                #pragma unroll
                for (int q = 0; q < 4; ++q){
                    const float i_ = sigmoid_fast(A0[0][q] + A1[0][q]);
                    const float f_ = sigmoid_fast(A0[1][q] + A1[1][q]);
                    const float g_ = tanh_fast   (A0[2][q] + A1[2][q]);
                    const float o_ = sigmoid_fast(A0[3][q] + A1[3][q]);
                    cc[q] = fmaf(f_, cc[q], i_ * g_);
                    const float h1v = o_ * tanh_fast(cc[q]);
                    unsigned short h, l; bf16_split(h1v, h, l);
                    HH[q] = h; HL[q] = l;
                }
                *(ush4*)&i1h[nxt][bb][32 + uo] = HH;
                *(ush4*)&i1l[nxt][bb][32 + uo] = HL;
                *(ush4*)&i2h[nxt][bb][uo]      = HH;
                *(ush4*)&i2l[nxt][bb][uo]      = HL;
            }
        } else if (wid < 6){
            if (t > 0){   // computes h2(t-1)
                const unsigned short* ph = &i2h[cur][0][0] + bb*IMW + 8*kg;
                const unsigned short* pl = &i2l[cur][0][0] + bb*IMW + 8*kg;
                bf16x8 vh[3], vl[3];
                #pragma unroll
                for (int kb = 0; kb < 3; ++kb){
                    vh[kb] = *(const bf16x8*)(ph + 32*kb);
                    vl[kb] = *(const bf16x8*)(pl + 32*kb);
                }
                f32x4 A0[4], A1[4];
                #pragma unroll
                for (int g = 0; g < 4; ++g){ A0[g] = bfr[g]; A1[g] = {0.f,0.f,0.f,0.f}; }
                #pragma unroll
                for (int kb = 0; kb < 3; ++kb)
                    #pragma unroll
                    for (int g = 0; g < 4; ++g) A0[g] = MFMA(wh[g][kb], vh[kb], A0[g]);
                #pragma unroll
                for (int kb = 0; kb < 3; ++kb)
                    #pragma unroll
                    for (int g = 0; g < 4; ++g) A1[g] = MFMA(wl[g][kb], vh[kb], A1[g]);
                #pragma unroll
                for (int g = 0; g < 4; ++g) A0[g] = MFMA(wh[g][0], vl[0], A0[g]);
                #pragma unroll
                for (int g = 0; g < 4; ++g){
                    A1[g] = MFMA(wh[g][1], vl[1], A1[g]);
                    A1[g] = MFMA(wh[g][2], vl[2], A1[g]);
                }
                ush4 HH, HL;
                f32x4 hv;
                #pragma unroll
                for (int q = 0; q < 4; ++q){
                    const float i_ = sigmoid_fast(A0[0][q] + A1[0][q]);
                    const float f_ = sigmoid_fast(A0[1][q] + A1[1][q]);
                    const float g_ = tanh_fast   (A0[2][q] + A1[2][q]);
                    const float o_ = sigmoid_fast(A0[3][q] + A1[3][q]);
                    cc[q] = fmaf(f_, cc[q], i_ * g_);
                    const float h2v = o_ * tanh_fast(cc[q]);
                    unsigned short h, l; bf16_split(h2v, h, l);
                    HH[q] = h; HL[q] = l; hv[q] = h2v;
                }
                *(ush4*)&i2h[nxt][bb][64 + uo] = HH;
                *(ush4*)&i2l[nxt][bb][64 + uo] = HL;
                if (t == T_) *(f32x4*)&hfin[bb][uo] = hv;
            }
        } else {
            const int tp1 = t + 1;
            if (tp1 < T_ && (((tp1 >> 3) & 1) == xw)){
                // stage x(tp1) from xr0 (register-rotated, all static indices)
                ush4 HH, HL;
                unsigned short h, l;
                bf16_split(xr0.x, h, l); HH[0]=h; HL[0]=l;
                bf16_split(xr0.y, h, l); HH[1]=h; HL[1]=l;
                bf16_split(xr0.z, h, l); HH[2]=h; HL[2]=l;
                bf16_split(xr0.w, h, l); HH[3]=h; HL[3]=l;
                *(ush4*)&i1h[nxt][xb_][4*xf4] = HH;
                *(ush4*)&i1l[nxt][xb_][4*xf4] = HL;
                xr0=xr1; xr1=xr2; xr2=xr3; xr3=xr4; xr4=xr5; xr5=xr6; xr6=xr7;
                if ((tp1 & 7) == 7){
                    const int gn = (tp1 >> 3) + 2;   // next group this wave owns
                    if (gn <= T_/8 - 1){
                        const size_t gb = xbase + (size_t)(8*gn) * F_;
                        // burst-issue 8 loads; they stay in flight across the
                        // raw barriers (no vmcnt drain) and are consumed 8
                        // steps later -- latency fully hidden by compute
                        xr0 = *(const float4*)&x[gb + 0*F_];
                        xr1 = *(const float4*)&x[gb + 1*F_];
                        xr2 = *(const float4*)&x[gb + 2*F_];
                        xr3 = *(const float4*)&x[gb + 3*F_];
                        xr4 = *(const float4*)&x[gb + 4*F_];
                        xr5 = *(const float4*)&x[gb + 5*F_];
                        xr6 = *(const float4*)&x[gb + 6*F_];
                        xr7 = *(const float4*)&x[gb + 7*F_];
                    }
                }
            }
        }
        step_barrier();
    }

    __syncthreads();
    // ===== head: fc1(16)+relu, fc2(1) =====
    if (tid < NBB * 16){
        const int b = tid >> 4, j2 = tid & 15;
        float a = b_fc1[j2];
        #pragma unroll
        for (int k = 0; k < 32; ++k) a = fmaf(W_fc1[j2*32 + k], hfin[b][k], a);
        hd[b][j2] = fmaxf(a, 0.f);
    }
    __syncthreads();
    if (tid < NBB){
        float a = b_fc2[0];
        #pragma unroll
        for (int k = 0; k < 16; ++k) a = fmaf(W_fc2[k], hd[tid][k], a);
        out[b0 + tid] = a;
    }
}

extern "C" void kernel_launch(void* const* d_in, const int* in_sizes, int n_in,
                              void* d_out, int out_size, void* d_ws, size_t ws_size,
                              hipStream_t stream) {
    const float* x     = (const float*)d_in[0];
    const float* W_ih1 = (const float*)d_in[1];
    const float* W_hh1 = (const float*)d_in[2];
    const float* b_ih1 = (const float*)d_in[3];
    const float* b_hh1 = (const float*)d_in[4];
    const float* W_ih2 = (const float*)d_in[5];
    const float* W_hh2 = (const float*)d_in[6];
    const float* b_ih2 = (const float*)d_in[7];
    const float* b_hh2 = (const float*)d_in[8];
    const float* W_fc1 = (const float*)d_in[9];
    const float* b_fc1 = (const float*)d_in[10];
    const float* W_fc2 = (const float*)d_in[11];
    const float* b_fc2 = (const float*)d_in[12];
    float* out = (float*)d_out;

    const int B = in_sizes[0] / (T_ * F_);   // 4096
    dim3 grid(B / NBB), block(TPB);          // 512 blocks = 2 per CU
    hipLaunchKernelGGL(lstm_mfma, grid, block, 0, stream,
                       x, W_ih1, W_hh1, b_ih1, b_hh1,
                       W_ih2, W_hh2, b_ih2, b_hh2,
                       W_fc1, b_fc1, W_fc2, b_fc2, out);
}

// Round 9
// 334.164 us; speedup vs baseline: 6.1198x; 2.8597x over previous
//
#include <hip/hip_runtime.h>

#define T_   256
#define F_   32
#define NBB  16
#define TPB  512
#define IMW  104
#define PR1  260   // pre1 row stride (f32); 16B-aligned rows, 2-way banks max
#define PR2  132   // pre2 row stride

typedef __attribute__((ext_vector_type(8))) short bf16x8;
typedef __attribute__((ext_vector_type(4))) float f32x4;

#define K1f  (-1.44269504f)   // -log2(e)   : sigmoid gates
#define K2f  (-2.88539008f)   // -2*log2(e) : tanh gate & tanh(c)

__device__ __forceinline__ unsigned short bf16_rne(float x){
    unsigned u = __float_as_uint(x);
    u += 0x7FFF + ((u >> 16) & 1);
    return (unsigned short)(u >> 16);
}
__device__ __forceinline__ void bf16_split(float x, unsigned short& h, unsigned short& l){
    h = bf16_rne(x);
    float xr = __uint_as_float(((unsigned)h) << 16);
    l = bf16_rne(x - xr);
}
__device__ __forceinline__ void make_frags_s(const float* __restrict__ p8, float s,
                                             bf16x8& fh, bf16x8& fl){
    #pragma unroll
    for (int e = 0; e < 8; ++e){
        unsigned short h, l; bf16_split(s * p8[e], h, l);
        fh[e] = (short)h; fl[e] = (short)l;
    }
}
// preact p is PRE-SCALED: p = -log2e*x  ->  sigmoid(x) = rcp(1+2^p)       (3 ops)
__device__ __forceinline__ float sigm_pre(float p){
    return __builtin_amdgcn_rcpf(1.f + __builtin_amdgcn_exp2f(p));
}
// p = -2log2e*x  ->  tanh(x) = 2*rcp(1+2^p) - 1                           (4 ops)
__device__ __forceinline__ float tanh_pre(float p){
    return fmaf(2.f, __builtin_amdgcn_rcpf(1.f + __builtin_amdgcn_exp2f(p)), -1.f);
}

#define MFMA(A,B,C) __builtin_amdgcn_mfma_f32_16x16x32_bf16((A),(B),(C),0,0,0)

// LDS-visibility barrier WITHOUT vmcnt drain: x-loads (register dest, consumed
// a full step later) stay in flight across it.
__device__ __forceinline__ void step_barrier(){
    asm volatile("s_waitcnt lgkmcnt(0)" ::: "memory");
    __builtin_amdgcn_s_barrier();
}

// (512,2): 256-VGPR cap, ~150 natural -> 1 block/CU (by design; co-residency
// proven a dead end in r7/r8 -- per-step latency is NBB-invariant).
__global__ __launch_bounds__(TPB, 2) void lstm_mfma(
    const float* __restrict__ x,      // [4096,256,32]
    const float* __restrict__ W_ih1,  // [256,32]
    const float* __restrict__ W_hh1,  // [256,64]
    const float* __restrict__ b_ih1,  // [256]
    const float* __restrict__ b_hh1,  // [256]
    const float* __restrict__ W_ih2,  // [128,64]
    const float* __restrict__ W_hh2,  // [128,32]
    const float* __restrict__ b_ih2,  // [128]
    const float* __restrict__ b_hh2,  // [128]
    const float* __restrict__ W_fc1,  // [16,32]
    const float* __restrict__ b_fc1,  // [16]
    const float* __restrict__ W_fc2,  // [1,16]
    const float* __restrict__ b_fc2,  // [1]
    float* __restrict__ out)          // [4096]
{
    const int tid  = threadIdx.x;
    const int lane = tid & 63;
    const int wid  = tid >> 6;        // 0..7
    const int bb   = lane & 15;       // fragment col = batch
    const int kg   = (lane >> 4) & 3; // k-group of 8
    const int b0   = blockIdx.x * NBB;

    // img1 = [x(32)|h1(64)], img2 = [h1(64)|h2(32)]; hi/lo bf16, double-buffered
    __shared__ __align__(16) unsigned short i1h[2][NBB][IMW], i1l[2][NBB][IMW];
    __shared__ __align__(16) unsigned short i2h[2][NBB][IMW], i2l[2][NBB][IMW];
    __shared__ __align__(16) float pre1[NBB * PR1];   // scaled preacts incl bias
    __shared__ __align__(16) float pre2[NBB * PR2];
    __shared__ float hfin[NBB][32];
    __shared__ float hd[NBB][16];

    // ===== weight fragments (PRE-SCALED), round-4 proven tiling =====
    // waves 0-3: L1, wave w owns rows 64g+16w (all 4 gates)
    // waves 4-7: L2, wave j=wid-4 owns gate j (rows 32j..32j+31, two 16-row tiles)
    bf16x8 wh[4][3], wl[4][3];
    f32x4  bfr[4];
    if (wid < 4){
        #pragma unroll
        for (int g = 0; g < 4; ++g){
            const float s = (g == 2) ? K2f : K1f;
            const int r = 64*g + 16*wid + bb;
            make_frags_s(&W_ih1[r*32 +      8*kg], s, wh[g][0], wl[g][0]);
            make_frags_s(&W_hh1[r*64 +      8*kg], s, wh[g][1], wl[g][1]);
            make_frags_s(&W_hh1[r*64 + 32 + 8*kg], s, wh[g][2], wl[g][2]);
            #pragma unroll
            for (int q = 0; q < 4; ++q){
                const int row = 64*g + 16*wid + 4*kg + q;
                bfr[g][q] = s * (b_ih1[row] + b_hh1[row]);
            }
        }
    } else {
        const int j = wid - 4;
        const float s = (j == 2) ? K2f : K1f;
        #pragma unroll
        for (int tt = 0; tt < 2; ++tt){
            const int r = 32*j + 16*tt + bb;
            make_frags_s(&W_ih2[r*64 +      8*kg], s, wh[tt][0], wl[tt][0]);
            make_frags_s(&W_ih2[r*64 + 32 + 8*kg], s, wh[tt][1], wl[tt][1]);
            make_frags_s(&W_hh2[r*32 +      8*kg], s, wh[tt][2], wl[tt][2]);
            #pragma unroll
            for (int q = 0; q < 4; ++q){
                const int row = 32*j + 16*tt + 4*kg + q;
                bfr[tt][q] = s * (b_ih2[row] + b_hh2[row]);
            }
        }
    }

    // ===== combine ownership: thread (cb, uu) owns L1 units uu, uu+32 and L2 unit uu =====
    const int cb = tid >> 5;          // batch 0..15
    const int uu = tid & 31;
    float c1a = 0.f, c1b = 0.f, c2 = 0.f;

    // ===== x staging (tids 256-511): 2 floats each, loads 1 step ahead =====
    const int xi = tid - 256;
    const int xb = (xi >> 4) & 15;
    const int xf = (xi & 15) * 2;
    const size_t xbase = (size_t)(b0 + xb) * (T_*F_) + xf;
    float2 xc = make_float2(0.f, 0.f);

    // ===== init: zero images, stage x(0), preload x(1) =====
    for (int i = tid; i < 2*NBB*IMW; i += TPB){
        (&i1h[0][0][0])[i] = 0; (&i1l[0][0][0])[i] = 0;
        (&i2h[0][0][0])[i] = 0; (&i2l[0][0][0])[i] = 0;
    }
    __syncthreads();
    if (tid >= 256){
        float2 x0 = *(const float2*)&x[xbase];
        unsigned short hh, hl;
        bf16_split(x0.x, hh, hl); i1h[0][xb][xf]   = hh; i1l[0][xb][xf]   = hl;
        bf16_split(x0.y, hh, hl); i1h[0][xb][xf+1] = hh; i1l[0][xb][xf+1] = hl;
        xc = *(const float2*)&x[xbase + F_];
    }
    __syncthreads();

    // ===== main loop: 2 phases, 2 raw barriers; L2 lags L1 by one step =====
    for (int t = 0; t <= T_; ++t){
        const int cur = t & 1, nxt = cur ^ 1;

        // ---- phase 1: MFMA -> preact LDS ----
        if (wid < 4){
            if (t < T_){
                const unsigned short* ph = &i1h[cur][0][0] + bb*IMW + 8*kg;
                const unsigned short* pl = &i1l[cur][0][0] + bb*IMW + 8*kg;
                bf16x8 vh[3], vl[3];
                #pragma unroll
                for (int kb = 0; kb < 3; ++kb){
                    vh[kb] = *(const bf16x8*)(ph + 32*kb);
                    vl[kb] = *(const bf16x8*)(pl + 32*kb);
                }
                #pragma unroll
                for (int g = 0; g < 4; ++g){
                    f32x4 a = bfr[g];
                    #pragma unroll
                    for (int kb = 0; kb < 3; ++kb) a = MFMA(wh[g][kb], vh[kb], a);
                    #pragma unroll
                    for (int kb = 0; kb < 3; ++kb) a = MFMA(wl[g][kb], vh[kb], a);
                    #pragma unroll
                    for (int kb = 0; kb < 3; ++kb) a = MFMA(wh[g][kb], vl[kb], a);
                    *(f32x4*)&pre1[bb*PR1 + 64*g + 16*wid + 4*kg] = a;
                }
            }
        } else {
            if (t > 0){
                const int j = wid - 4;
                const unsigned short* ph = &i2h[cur][0][0] + bb*IMW + 8*kg;
                const unsigned short* pl = &i2l[cur][0][0] + bb*IMW + 8*kg;
                bf16x8 vh[3], vl[3];
                #pragma unroll
                for (int kb = 0; kb < 3; ++kb){
                    vh[kb] = *(const bf16x8*)(ph + 32*kb);
                    vl[kb] = *(const bf16x8*)(pl + 32*kb);
                }
                #pragma unroll
                for (int tt = 0; tt < 2; ++tt){
                    f32x4 a = bfr[tt];
                    #pragma unroll
                    for (int kb = 0; kb < 3; ++kb) a = MFMA(wh[tt][kb], vh[kb], a);
                    #pragma unroll
                    for (int kb = 0; kb < 3; ++kb) a = MFMA(wl[tt][kb], vh[kb], a);
                    #pragma unroll
                    for (int kb = 0; kb < 3; ++kb) a = MFMA(wh[tt][kb], vl[kb], a);
                    *(f32x4*)&pre2[bb*PR2 + 32*j + 16*tt + 4*kg] = a;
                }
            }
        }
        step_barrier();   // pre1/pre2 visible; img[cur] reads done

        // ---- phase 2: uniform combine (3 units/thread) + img[nxt] writes ----
        if (t < T_){
            const float* p = &pre1[cb*PR1];
            #pragma unroll
            for (int s2 = 0; s2 < 2; ++s2){
                const int u = uu + 32*s2;
                const float i_ = sigm_pre(p[u]);
                const float f_ = sigm_pre(p[64 + u]);
                const float g_ = tanh_pre(p[128 + u]);
                const float o_ = sigm_pre(p[192 + u]);
                const float cp = s2 ? c1b : c1a;
                const float c  = fmaf(f_, cp, i_ * g_);
                if (s2) c1b = c; else c1a = c;
                const float h  = o_ * tanh_pre(K2f * c);
                unsigned short hh, hl; bf16_split(h, hh, hl);
                i1h[nxt][cb][32 + u] = hh; i1l[nxt][cb][32 + u] = hl;
                i2h[nxt][cb][u]      = hh; i2l[nxt][cb][u]      = hl;
            }
        }
        if (t > 0){
            const float* p = &pre2[cb*PR2];
            const float i_ = sigm_pre(p[uu]);
            const float f_ = sigm_pre(p[32 + uu]);
            const float g_ = tanh_pre(p[64 + uu]);
            const float o_ = sigm_pre(p[96 + uu]);
            c2 = fmaf(f_, c2, i_ * g_);
            const float h2 = o_ * tanh_pre(K2f * c2);
            unsigned short hh, hl; bf16_split(h2, hh, hl);
            i2h[nxt][cb][64 + uu] = hh; i2l[nxt][cb][64 + uu] = hl;
            if (t == T_) hfin[cb][uu] = h2;
        }
        if (tid >= 256 && t + 1 < T_){
            // stage x(t+1) (loaded a full step ago); issue load of x(t+2)
            unsigned short hh, hl;
            bf16_split(xc.x, hh, hl); i1h[nxt][xb][xf]   = hh; i1l[nxt][xb][xf]   = hl;
            bf16_split(xc.y, hh, hl); i1h[nxt][xb][xf+1] = hh; i1l[nxt][xb][xf+1] = hl;
            const int tn = (t + 2 < T_) ? t + 2 : T_ - 1;
            xc = *(const float2*)&x[xbase + (size_t)tn * F_];
        }
        step_barrier();
    }

    __syncthreads();
    // ===== head: fc1(16)+relu, fc2(1) =====
    if (tid < NBB * 16){
        const int b = tid >> 4, j2 = tid & 15;
        float a = b_fc1[j2];
        #pragma unroll
        for (int k = 0; k < 32; ++k) a = fmaf(W_fc1[j2*32 + k], hfin[b][k], a);
        hd[b][j2] = fmaxf(a, 0.f);
    }
    __syncthreads();
    if (tid < NBB){
        float a = b_fc2[0];
        #pragma unroll
        for (int k = 0; k < 16; ++k) a = fmaf(W_fc2[k], hd[tid][k], a);
        out[b0 + tid] = a;
    }
}

extern "C" void kernel_launch(void* const* d_in, const int* in_sizes, int n_in,
                              void* d_out, int out_size, void* d_ws, size_t ws_size,
                              hipStream_t stream) {
    const float* x     = (const float*)d_in[0];
    const float* W_ih1 = (const float*)d_in[1];
    const float* W_hh1 = (const float*)d_in[2];
    const float* b_ih1 = (const float*)d_in[3];
    const float* b_hh1 = (const float*)d_in[4];
    const float* W_ih2 = (const float*)d_in[5];
    const float* W_hh2 = (const float*)d_in[6];
    const float* b_ih2 = (const float*)d_in[7];
    const float* b_hh2 = (const float*)d_in[8];
    const float* W_fc1 = (const float*)d_in[9];
    const float* b_fc1 = (const float*)d_in[10];
    const float* W_fc2 = (const float*)d_in[11];
    const float* b_fc2 = (const float*)d_in[12];
    float* out = (float*)d_out;

    const int B = in_sizes[0] / (T_ * F_);   // 4096
    dim3 grid(B / NBB), block(TPB);          // 256 blocks, 1/CU
    hipLaunchKernelGGL(lstm_mfma, grid, block, 0, stream,
                       x, W_ih1, W_hh1, b_ih1, b_hh1,
                       W_ih2, W_hh2, b_ih2, b_hh2,
                       W_fc1, b_fc1, W_fc2, b_fc2, out);
}